// Round 12
// baseline (78.708 us; speedup 1.0000x reference)
//
#include <hip/hip_runtime.h>
#include <math.h>

#define Nn 8192
#define Dd 256
#define NBINS 64

typedef __attribute__((ext_vector_type(8))) short short8;
typedef __attribute__((ext_vector_type(4))) float f32x4;

#define GLOAD16(g, l)                                                        \
  __builtin_amdgcn_global_load_lds(                                          \
      (const __attribute__((address_space(1))) void*)(g),                    \
      (__attribute__((address_space(3))) void*)(l), 16, 0, 0)

static __device__ __forceinline__ unsigned short f2bf(float f) {
  unsigned int u = __float_as_uint(f);
  u = (u + 0x7fffu + ((u >> 16) & 1u)) >> 16;  // RNE
  return (unsigned short)u;
}
// order-preserving bijection float -> uint (atomicMax/Min on uint handles negatives)
static __device__ __forceinline__ unsigned int enc_ord(float f) {
  unsigned int u = __float_as_uint(f);
  return (u & 0x80000000u) ? ~u : (u | 0x80000000u);
}
static __device__ __forceinline__ float dec_ord(unsigned int u) {
  unsigned int b2 = (u & 0x80000000u) ? (u ^ 0x80000000u) : ~u;
  return __uint_as_float(b2);
}

// ---------------- K0: bf16 cast + fused (norm,label) + init accumulators ----------------
__global__ __launch_bounds__(256) void prep_kernel(const float* __restrict__ x,
                                                   const int* __restrict__ lab,
                                                   unsigned short* __restrict__ xb,
                                                   float2* __restrict__ sqlab,
                                                   unsigned int* __restrict__ pos2,
                                                   unsigned int* __restrict__ neg2,
                                                   unsigned int* __restrict__ gmm,
                                                   float* __restrict__ ghist,
                                                   float* __restrict__ ghsum) {
  const int w = threadIdx.x >> 6;
  const int lane = threadIdx.x & 63;
  const int row = blockIdx.x * 4 + w;
  const float4 v = *(const float4*)(x + (size_t)row * Dd + lane * 4);
  ushort4 b;
  b.x = f2bf(v.x); b.y = f2bf(v.y); b.z = f2bf(v.z); b.w = f2bf(v.w);
  *(ushort4*)(xb + (size_t)row * Dd + lane * 4) = b;
  float s = v.x * v.x + v.y * v.y + v.z * v.z + v.w * v.w;
#pragma unroll
  for (int off = 32; off >= 1; off >>= 1) s += __shfl_xor(s, off);
  if (lane == 0) {
    sqlab[row] = make_float2(s, __int_as_float(lab[row]));
    pos2[row] = 0x007fffffu;  // enc_ord(-inf)
    neg2[row] = 0xff800000u;  // enc_ord(+inf)
  }
  if (blockIdx.x == 0 && threadIdx.x < NBINS) {
    ghist[threadIdx.x] = 0.0f;
    ghsum[threadIdx.x] = 0.0f;
    if (threadIdx.x == 0) { gmm[0] = 0x007fffffu; gmm[1] = 0xff800000u; }
  }
}

// stage one A half-K tile (128 rows x 128 k = 32KB), XOR chunk placement, 256 threads
static __device__ __forceinline__ void stage_a(const unsigned short* __restrict__ xb,
                                               int r0, int hh, unsigned short* buf, int t) {
#pragma unroll
  for (int i = 0; i < 8; ++i) {
    const int c = i * 256 + t;          // 0..2047
    const int col = c >> 4;             // 0..127
    const int kq = (c & 15) ^ (col & 15);
    GLOAD16(xb + (size_t)(r0 + col) * Dd + hh * 128 + kq * 8, buf + (size_t)c * 8);
  }
}
// stage one B half-K tile (64 cols x 128 k = 16KB), exactly 4 global_load_lds per wave
static __device__ __forceinline__ void stage_b(const unsigned short* __restrict__ xb,
                                               int c0, int hh, unsigned short* buf, int t) {
#pragma unroll
  for (int i = 0; i < 4; ++i) {
    const int c = i * 256 + t;          // 0..1023
    const int col = c >> 4;             // 0..63
    const int kq = (c & 15) ^ (col & 15);
    GLOAD16(xb + (size_t)(c0 + col) * Dd + hh * 128 + kq * 8, buf + (size_t)c * 8);
  }
}

// ---------------- K1: TRIANGULAR MFMA Gram + fused row+col masked max/min ----------------
// Symmetry: dist(i,j)=dist(j,i) -> only col tiles c >= 2*bi are computed (50.8% of full).
// Each tile updates BOTH the row rows (g = sq_col - 2acc, running regs) and the col rows
// (w = sq_row - 2acc, LDS-accumulated colP/colN, flushed once per block). Same encoding
// (stored value excludes own norm, finalize adds sq[i]); max/min idempotent -> diagonal
// tiles' redundant col updates are harmless. r11's 3-buffer ring + vmcnt(4) kept verbatim.
__global__ __launch_bounds__(256, 2) void pairwise_kernel(const unsigned short* __restrict__ xb,
                                                          const float2* __restrict__ sqlab,
                                                          unsigned int* __restrict__ pos2,
                                                          unsigned int* __restrict__ neg2) {
  __shared__ __align__(16) unsigned short Us[4096 * 8];  // 64KB flat: A stage; then ring+col+sl
  __shared__ float rowsl[128];
  __shared__ int lab_s[128];

  const int t = threadIdx.x;   // 0..255
  const int lane = t & 63;
  const int w = t >> 6;        // 0..3
  const int wr = w >> 1;       // row half
  const int wc = w & 1;        // col half of 64
  const int c_l = lane & 15;
  const int kq_l = lane >> 4;

  // balanced triangular mapping: interleave heavy(low bi)/light(high bi) blocks
  const int s = blockIdx.x & 7;
  const int q = blockIdx.x >> 3;                       // 0..63
  const int bi = (q & 1) ? (63 - (q >> 1)) : (q >> 1); // permutation of 0..63
  const int rows0 = bi * 128;
  const int c0 = 2 * bi + ((s - 2 * bi) & 7);          // first 64-col tile >= diagonal, == s mod 8
  if (c0 >= 128) return;                               // nothing to do (light tail blocks)
  const int nct = (128 - c0 + 7) >> 3;                 // 1..16 tiles

  // ---- stage A (both K halves) into Us[0..64KB); row norms+labels ----
  stage_a(xb, rows0, 0, Us, t);
  stage_a(xb, rows0, 1, Us + 2048 * 8, t);
  if (t < 128) {
    const float2 v = sqlab[rows0 + t];
    rowsl[t] = v.x;
    lab_s[t] = __float_as_int(v.y);
  }
  __syncthreads();  // full drain (one-time)

  // ---- A fragments -> registers (forced residency: Us overwritten below) ----
  const short8* Uv = (const short8*)Us;
  short8 af[32];
#pragma unroll
  for (int k2 = 0; k2 < 8; ++k2)
#pragma unroll
    for (int m = 0; m < 4; ++m) {
      const int kqf = k2 * 4 + kq_l;
      const int rl = wr * 64 + m * 16 + c_l;
      af[k2 * 4 + m] = Uv[(kqf >> 4) * 2048 + rl * 16 + ((kqf & 15) ^ (rl & 15))];
    }
  int labp[8];
#pragma unroll
  for (int m = 0; m < 4; ++m)
#pragma unroll
    for (int pp = 0; pp < 2; ++pp) {
      const int r0 = wr * 64 + m * 16 + kq_l * 4 + 2 * pp;
      labp[m * 2 + pp] = (lab_s[r0] & 0xffff) | (lab_s[r0 + 1] << 16);
    }
  __syncthreads();  // af/lab reads done before regions repurposed

  // region map (short offsets): ring 3x16KB [0,24576); colP [24576,26624);
  // colN [26624,28672); sl (float2[1024]) [28672,32768)
  unsigned short* const B0 = Us;
  unsigned short* const B1 = Us + 1024 * 8;
  unsigned short* const B2 = Us + 2048 * 8;
  unsigned int* const colP = (unsigned int*)(Us + 24576);
  unsigned int* const colN = (unsigned int*)(Us + 26624);
  float2* const slv = (float2*)(Us + 28672);

  // init col accumulators + stage (sq,label) for this block's columns
#pragma unroll
  for (int i = 0; i < 4; ++i) {
    colP[i * 256 + t] = 0x007fffffu;  // enc_ord(-inf)
    colN[i * 256 + t] = 0xff800000u;  // enc_ord(+inf)
  }
  for (int i = t; i < nct * 64; i += 256) {
    const int cc = c0 + 8 * (i >> 6);
    slv[i] = sqlab[cc * 64 + (i & 63)];
  }
  __syncthreads();  // LDS writes visible AND all prologue VMEM drained -> vmcnt exact

  // ring prologue: first tile's two halves (8 loads in flight per wave)
  stage_b(xb, c0 * 64, 0, B0, t);
  stage_b(xb, c0 * 64, 1, B1, t);

  const int cc0 = wc * 32 + c_l;
  const int cc1 = wc * 32 + 16 + c_l;
  float pmax[16], nmin[16];
#pragma unroll
  for (int i = 0; i < 16; ++i) { pmax[i] = -INFINITY; nmin[i] = INFINITY; }

  int rA = 0;
#pragma unroll 1
  for (int o = 0; o < nct; ++o) {
    const int c = c0 + 8 * o;
    const int rB = (rA == 2) ? 0 : rA + 1;
    const int rC = (rB == 2) ? 0 : rB + 1;
    unsigned short* const bufA = (rA == 0) ? B0 : ((rA == 1) ? B1 : B2);
    unsigned short* const bufB = (rB == 0) ? B0 : ((rB == 1) ? B1 : B2);
    unsigned short* const bufC = (rC == 0) ? B0 : ((rC == 1) ? B1 : B2);
    const int cnext = ((o + 1 < nct) ? (c + 8) : c0) * 64;  // wrap = dead but in-bounds

    f32x4 acc[4][2];
#pragma unroll
    for (int m = 0; m < 4; ++m)
#pragma unroll
      for (int n = 0; n < 2; ++n) acc[m][n] = (f32x4){0.f, 0.f, 0.f, 0.f};

    // ---- even phase: consume bufA (k-half 0); stage next tile half0 -> bufC ----
    asm volatile("s_waitcnt vmcnt(4)" ::: "memory");
    __builtin_amdgcn_s_barrier();
    stage_b(xb, cnext, 0, bufC, t);
    {
      const short8* Bv = (const short8*)bufA;
#pragma unroll
      for (int ks = 0; ks < 4; ++ks) {
        const short8 bf0 = Bv[cc0 * 16 + ((ks * 4 + kq_l) ^ (cc0 & 15))];
        const short8 bf1 = Bv[cc1 * 16 + ((ks * 4 + kq_l) ^ (cc1 & 15))];
#pragma unroll
        for (int m = 0; m < 4; ++m) {
          acc[m][0] = __builtin_amdgcn_mfma_f32_16x16x32_bf16(af[ks * 4 + m], bf0, acc[m][0], 0, 0, 0);
          acc[m][1] = __builtin_amdgcn_mfma_f32_16x16x32_bf16(af[ks * 4 + m], bf1, acc[m][1], 0, 0, 0);
        }
      }
    }

    // ---- odd phase: consume bufB (k-half 1); stage next tile half1 -> bufA ----
    asm volatile("s_waitcnt vmcnt(4)" ::: "memory");
    __builtin_amdgcn_s_barrier();
    stage_b(xb, cnext, 1, bufA, t);
    {
      const short8* Bv = (const short8*)bufB;
#pragma unroll
      for (int ks = 0; ks < 4; ++ks) {
        const short8 bf0 = Bv[cc0 * 16 + ((ks * 4 + kq_l) ^ (cc0 & 15))];
        const short8 bf1 = Bv[cc1 * 16 + ((ks * 4 + kq_l) ^ (cc1 & 15))];
#pragma unroll
        for (int m = 0; m < 4; ++m) {
          acc[m][0] = __builtin_amdgcn_mfma_f32_16x16x32_bf16(af[(4 + ks) * 4 + m], bf0, acc[m][0], 0, 0, 0);
          acc[m][1] = __builtin_amdgcn_mfma_f32_16x16x32_bf16(af[(4 + ks) * 4 + m], bf1, acc[m][1], 0, 0, 0);
        }
      }
    }

    // ---- epilogue: row-side (registers) + col-side (LDS atomics) ----
    {
      const float2 sl0 = slv[o * 64 + cc0];
      const float2 sl1 = slv[o * 64 + cc1];
#pragma unroll
      for (int n = 0; n < 2; ++n) {
        const float sc = (n == 0) ? sl0.x : sl1.x;
        const int lc = __float_as_int((n == 0) ? sl0.y : sl1.y);
        float wp = -INFINITY, wn = INFINITY;
#pragma unroll
        for (int idx = 0; idx < 16; ++idx) {
          const int m = idx >> 2, qq = idx & 3;
          const float a2 = acc[m][n][qq];
          const int lr = (labp[idx >> 1] >> ((idx & 1) * 16)) & 0xffff;
          const bool same = (lr == lc);
          // row-side: value for row r = sq_col - 2acc
          const float g = fmaf(-2.0f, a2, sc);
          pmax[idx] = same ? fmaxf(pmax[idx], g) : pmax[idx];
          nmin[idx] = same ? nmin[idx] : fminf(nmin[idx], g);
          // col-side: value for col c = sq_row - 2acc (sq_row from LDS, no reg cost)
          const float wv = fmaf(-2.0f, a2, rowsl[wr * 64 + m * 16 + kq_l * 4 + qq]);
          wp = same ? fmaxf(wp, wv) : wp;
          wn = same ? wn : fminf(wn, wv);
        }
        // reduce over the 4 kq_l lanes holding this column, then LDS atomic
        wp = fmaxf(wp, __shfl_xor(wp, 16)); wp = fmaxf(wp, __shfl_xor(wp, 32));
        wn = fminf(wn, __shfl_xor(wn, 16)); wn = fminf(wn, __shfl_xor(wn, 32));
        if (lane < 16) {
          const int ci = o * 64 + ((n == 0) ? cc0 : cc1);
          atomicMax(&colP[ci], enc_ord(wp));
          atomicMin(&colN[ci], enc_ord(wn));
        }
      }
    }
    rA = rC;
  }

  // ---- flush col-side partials (batched, once per block) ----
  __syncthreads();
  for (int i = t; i < nct * 64; i += 256) {
    const int colg = (c0 + 8 * (i >> 6)) * 64 + (i & 63);
    atomicMax(&pos2[colg], colP[i]);
    atomicMin(&neg2[colg], colN[i]);
  }

  // ---- row-side: reduce over 16 col-lanes, 2 atomics per row ----
#pragma unroll
  for (int i = 0; i < 16; ++i) {
    float p = pmax[i], nn2 = nmin[i];
#pragma unroll
    for (int off = 1; off < 16; off <<= 1) {
      p = fmaxf(p, __shfl_xor(p, off));
      nn2 = fminf(nn2, __shfl_xor(nn2, off));
    }
    if (c_l == 0) {
      const int rowg = rows0 + wr * 64 + (i >> 2) * 16 + kq_l * 4 + (i & 3);
      atomicMax(&pos2[rowg], enc_ord(p));
      atomicMin(&neg2[rowg], enc_ord(nn2));
    }
  }
}

// ---------------- K2a: hv + global extremes (parallel) ----------------
__global__ __launch_bounds__(512) void finalize_a_kernel(const float2* __restrict__ sqlab,
                                                         const unsigned int* __restrict__ pos2,
                                                         const unsigned int* __restrict__ neg2,
                                                         float* __restrict__ hv_g,
                                                         unsigned int* __restrict__ gmm) {
  const int i = blockIdx.x * 512 + threadIdx.x;
  const int lane = threadIdx.x & 63;
  const float s = sqlab[i].x;
  const float p2 = fmaxf(s + dec_ord(pos2[i]), 1e-12f);
  const float n2 = fmaxf(s + dec_ord(neg2[i]), 1e-12f);
  const float hv = sqrtf(p2) - sqrtf(n2);
  hv_g[i] = hv;
  float lmax = hv, lmin = hv;
#pragma unroll
  for (int off = 32; off >= 1; off >>= 1) {
    lmax = fmaxf(lmax, __shfl_xor(lmax, off));
    lmin = fminf(lmin, __shfl_xor(lmin, off));
  }
  if (lane == 0) {
    atomicMax(&gmm[0], enc_ord(lmax));
    atomicMin(&gmm[1], enc_ord(lmin));
  }
}

// ---------------- K2b: per-block histogram + per-bin hv sums (parallel) ----------------
__global__ __launch_bounds__(512) void finalize_b_kernel(const float* __restrict__ hv_g,
                                                         const unsigned int* __restrict__ gmm,
                                                         float* __restrict__ ghist,
                                                         float* __restrict__ ghsum) {
  __shared__ float hist_s[NBINS];
  __shared__ float hsum_s[NBINS];
  const int t = threadIdx.x;
  if (t < NBINS) { hist_s[t] = 0.0f; hsum_s[t] = 0.0f; }
  const float maxv = fmaxf(dec_ord(gmm[0]), 2.0f);
  const float minv = fminf(dec_ord(gmm[1]), -2.0f);
  const float bw = (maxv - minv) / (float)(NBINS - 1);
  __syncthreads();

  const int i = blockIdx.x * 512 + t;
  const float hv = hv_g[i];
  int lo = (int)floorf((hv - minv) / bw);
  lo = min(max(lo, 0), NBINS - 1);
  const int hi = min(lo + 1, NBINS - 1);
  const float alpha = 1.0f - (hv - minv - (float)lo * bw) / bw;
  atomicAdd(&hist_s[lo], alpha);
  atomicAdd(&hist_s[hi], 1.0f - alpha);
  atomicAdd(&hsum_s[lo], hv);  // weight uses bin_idx = lo (same floor+clip)
  __syncthreads();

  if (t < NBINS) {
    atomicAdd(&ghist[t], hist_s[t]);
    atomicAdd(&ghsum[t], hsum_s[t]);
  }
}

// ---------------- K2c: cdf + loss (one wave) ----------------
__global__ __launch_bounds__(64) void finalize_c_kernel(const float* __restrict__ ghist,
                                                        const float* __restrict__ ghsum,
                                                        float* __restrict__ out) {
  const int t = threadIdx.x;
  const float h = ghist[t];
  float total = h;
#pragma unroll
  for (int off = 32; off >= 1; off >>= 1) total += __shfl_xor(total, off);
  const float hn = h / (total + 1e-6f);
  float s2 = hn;
#pragma unroll
  for (int off = 32; off >= 1; off >>= 1) s2 += __shfl_xor(s2, off);
  const float pdf = hn / s2;
  float c = pdf;
#pragma unroll
  for (int off = 1; off < 64; off <<= 1) {
    const float u = __shfl_up(c, off);
    if (t >= off) c += u;
  }
  float acc = c * ghsum[t];
#pragma unroll
  for (int off = 32; off >= 1; off >>= 1) acc += __shfl_xor(acc, off);
  if (t == 0) out[0] = acc / (float)Nn;
}

// ---------------- launch ----------------
extern "C" void kernel_launch(void* const* d_in, const int* in_sizes, int n_in,
                              void* d_out, int out_size, void* d_ws, size_t ws_size,
                              hipStream_t stream) {
  const float* x = (const float*)d_in[0];
  const int* targets = (const int*)d_in[1];
  float* out = (float*)d_out;

  char* p = (char*)d_ws;
  unsigned short* xb = (unsigned short*)p;  p += (size_t)Nn * Dd * 2;  // 4MB
  float2* sqlab = (float2*)p;               p += (size_t)Nn * 8;
  unsigned int* pos2 = (unsigned int*)p;    p += (size_t)Nn * 4;
  unsigned int* neg2 = (unsigned int*)p;    p += (size_t)Nn * 4;
  float* hv_g = (float*)p;                  p += (size_t)Nn * 4;
  unsigned int* gmm = (unsigned int*)p;     p += 64;
  float* ghist = (float*)p;                 p += NBINS * 4;
  float* ghsum = (float*)p;

  prep_kernel<<<Nn / 4, 256, 0, stream>>>(x, targets, xb, sqlab, pos2, neg2, gmm, ghist, ghsum);
  pairwise_kernel<<<512, 256, 0, stream>>>(xb, sqlab, pos2, neg2);
  finalize_a_kernel<<<Nn / 512, 512, 0, stream>>>(sqlab, pos2, neg2, hv_g, gmm);
  finalize_b_kernel<<<Nn / 512, 512, 0, stream>>>(hv_g, gmm, ghist, ghsum);
  finalize_c_kernel<<<1, 64, 0, stream>>>(ghist, ghsum, out);
}

// Round 13
// 63.014 us; speedup vs baseline: 1.2491x; 1.2491x over previous
//
#include <hip/hip_runtime.h>
#include <math.h>

#define Nn 8192
#define Dd 256
#define NBINS 64
#define NSPLIT 8

typedef __attribute__((ext_vector_type(8))) short short8;
typedef __attribute__((ext_vector_type(4))) float f32x4;

#define GLOAD16(g, l)                                                        \
  __builtin_amdgcn_global_load_lds(                                          \
      (const __attribute__((address_space(1))) void*)(g),                    \
      (__attribute__((address_space(3))) void*)(l), 16, 0, 0)

static __device__ __forceinline__ unsigned short f2bf(float f) {
  unsigned int u = __float_as_uint(f);
  u = (u + 0x7fffu + ((u >> 16) & 1u)) >> 16;  // RNE
  return (unsigned short)u;
}
// order-preserving bijection float -> uint (atomicMax/Min on uint handles negatives)
static __device__ __forceinline__ unsigned int enc_ord(float f) {
  unsigned int u = __float_as_uint(f);
  return (u & 0x80000000u) ? ~u : (u | 0x80000000u);
}
static __device__ __forceinline__ float dec_ord(unsigned int u) {
  unsigned int b2 = (u & 0x80000000u) ? (u ^ 0x80000000u) : ~u;
  return __uint_as_float(b2);
}

// ---------------- K0: bf16 cast + fused (norm,label) + init accumulators ----------------
__global__ __launch_bounds__(256) void prep_kernel(const float* __restrict__ x,
                                                   const int* __restrict__ lab,
                                                   unsigned short* __restrict__ xb,
                                                   float2* __restrict__ sqlab,
                                                   unsigned int* __restrict__ pos2,
                                                   unsigned int* __restrict__ neg2,
                                                   unsigned int* __restrict__ gmm,
                                                   float* __restrict__ ghist,
                                                   float* __restrict__ ghsum) {
  const int w = threadIdx.x >> 6;
  const int lane = threadIdx.x & 63;
  const int row = blockIdx.x * 4 + w;
  const float4 v = *(const float4*)(x + (size_t)row * Dd + lane * 4);
  ushort4 b;
  b.x = f2bf(v.x); b.y = f2bf(v.y); b.z = f2bf(v.z); b.w = f2bf(v.w);
  *(ushort4*)(xb + (size_t)row * Dd + lane * 4) = b;
  float s = v.x * v.x + v.y * v.y + v.z * v.z + v.w * v.w;
#pragma unroll
  for (int off = 32; off >= 1; off >>= 1) s += __shfl_xor(s, off);
  if (lane == 0) {
    sqlab[row] = make_float2(s, __int_as_float(lab[row]));
    pos2[row] = 0x007fffffu;  // enc_ord(-inf)
    neg2[row] = 0xff800000u;  // enc_ord(+inf)
  }
  if (blockIdx.x == 0 && threadIdx.x < NBINS) {
    ghist[threadIdx.x] = 0.0f;
    ghsum[threadIdx.x] = 0.0f;
    if (threadIdx.x == 0) { gmm[0] = 0x007fffffu; gmm[1] = 0xff800000u; }
  }
}

// stage one A half-K tile (128 rows x 128 k = 32KB), XOR chunk placement, 256 threads
static __device__ __forceinline__ void stage_a(const unsigned short* __restrict__ xb,
                                               int r0, int hh, unsigned short* buf, int t) {
#pragma unroll
  for (int i = 0; i < 8; ++i) {
    const int c = i * 256 + t;          // 0..2047
    const int col = c >> 4;             // 0..127
    const int kq = (c & 15) ^ (col & 15);
    GLOAD16(xb + (size_t)(r0 + col) * Dd + hh * 128 + kq * 8, buf + (size_t)c * 8);
  }
}
// stage one B half-K tile (64 cols x 128 k = 16KB), 4 global_load_lds per thread
static __device__ __forceinline__ void stage_b(const unsigned short* __restrict__ xb,
                                               int c0, int hh, unsigned short* buf, int t) {
#pragma unroll
  for (int i = 0; i < 4; ++i) {
    const int c = i * 256 + t;          // 0..1023
    const int col = c >> 4;             // 0..63
    const int kq = (c & 15) ^ (col & 15);
    GLOAD16(xb + (size_t)(c0 + col) * Dd + hh * 128 + kq * 8, buf + (size_t)c * 8);
  }
}

// ---------------- K1: MFMA Gram + fused masked max/min (1 barrier/tile, full-tile dbuf) ----------------
// r11 geometry (4 waves, 64x32 wave tiles, 128x64 ct tiles, 2 blocks/CU, A in 128 VGPRs).
// Schedule change: per tile ONE __syncthreads, then stage BOTH K-halves of tile ct+1 into
// the other 32KB buffer (8 loads), then compute both MFMA phases + epilogue from the
// current buffer. The barrier's implicit vmcnt(0) drains loads issued a FULL TILE earlier
// (~1500cy, L2-resident source) -> zero stall; barrier count halves vs r11.
__global__ __launch_bounds__(256, 2) void pairwise_kernel(const unsigned short* __restrict__ xb,
                                                          const float2* __restrict__ sqlab,
                                                          unsigned int* __restrict__ pos2,
                                                          unsigned int* __restrict__ neg2) {
  __shared__ __align__(16) unsigned short Us[4096 * 8];  // 64KB: A staging, then 2x32KB B dbuf
  __shared__ __align__(16) float2 sl_s[1024];            // 8KB (sq,label) for this col split
  __shared__ int lab_s[128];

  const int t = threadIdx.x;   // 0..255
  const int lane = t & 63;
  const int w = t >> 6;        // 0..3
  const int wr = w >> 1;       // 0..1 (row half)
  const int wc = w & 1;        // 0..1 (col half of 64)
  const int c_l = lane & 15;
  const int kq_l = lane >> 4;
  const int rows0 = blockIdx.x * 128;
  const int cbase = blockIdx.y * (Nn / NSPLIT);

  // ---- stage A (both K halves) into Us; stage sl_s + labels ----
  stage_a(xb, rows0, 0, Us, t);
  stage_a(xb, rows0, 1, Us + 2048 * 8, t);
#pragma unroll
  for (int i = 0; i < 4; ++i) sl_s[i * 256 + t] = sqlab[cbase + i * 256 + t];
  if (t < 128) lab_s[t] = __float_as_int(sqlab[rows0 + t].y);
  __syncthreads();  // A staged (implicit vmcnt(0))

  // ---- A fragments -> registers (forced residency: Us gets overwritten by B dbuf) ----
  const short8* Uv = (const short8*)Us;
  short8 af[32];
#pragma unroll
  for (int k2 = 0; k2 < 8; ++k2)
#pragma unroll
    for (int m = 0; m < 4; ++m) {
      const int kqf = k2 * 4 + kq_l;               // global k-octet 0..31
      const int rl = wr * 64 + m * 16 + c_l;       // local row 0..127
      af[k2 * 4 + m] = Uv[(kqf >> 4) * 2048 + rl * 16 + ((kqf & 15) ^ (rl & 15))];
    }
  int labp[8];
#pragma unroll
  for (int m = 0; m < 4; ++m)
#pragma unroll
    for (int pp = 0; pp < 2; ++pp) {
      const int r0 = wr * 64 + m * 16 + kq_l * 4 + 2 * pp;
      labp[m * 2 + pp] = (lab_s[r0] & 0xffff) | (lab_s[r0 + 1] << 16);
    }
  __syncthreads();  // af/lab reads done before B dbuf overwrites Us

  unsigned short* const Bs0 = Us;               // 32KB (half0 at +0, half1 at +16KB)
  unsigned short* const Bs1 = Us + 2048 * 8;    // 32KB

  // prologue: tile 0 (both halves) -> Bs0
  stage_b(xb, cbase, 0, Bs0, t);
  stage_b(xb, cbase, 1, Bs0 + 1024 * 8, t);

  const int cc0 = wc * 32 + c_l;        // local col
  const int cc1 = wc * 32 + 16 + c_l;
  float pmax[16], nmin[16];
#pragma unroll
  for (int i = 0; i < 16; ++i) { pmax[i] = -INFINITY; nmin[i] = INFINITY; }

  int cur = 0;
#pragma unroll 1
  for (int ct = 0; ct < 16; ++ct) {
    unsigned short* const bufR = cur ? Bs1 : Bs0;
    unsigned short* const bufW = cur ? Bs0 : Bs1;

    __syncthreads();  // bufR's 8 loads (issued one full tile ago) drained; bufW free (reads done)
    if (ct < 15) {
      stage_b(xb, cbase + (ct + 1) * 64, 0, bufW, t);
      stage_b(xb, cbase + (ct + 1) * 64, 1, bufW + 1024 * 8, t);
    }

    f32x4 acc[4][2];
#pragma unroll
    for (int m = 0; m < 4; ++m)
#pragma unroll
      for (int n = 0; n < 2; ++n) acc[m][n] = (f32x4){0.f, 0.f, 0.f, 0.f};

    // ---- k-half 0 ----
    {
      const short8* Bv = (const short8*)bufR;
#pragma unroll
      for (int ks = 0; ks < 4; ++ks) {
        const short8 bf0 = Bv[cc0 * 16 + ((ks * 4 + kq_l) ^ (cc0 & 15))];
        const short8 bf1 = Bv[cc1 * 16 + ((ks * 4 + kq_l) ^ (cc1 & 15))];
#pragma unroll
        for (int m = 0; m < 4; ++m) {
          acc[m][0] = __builtin_amdgcn_mfma_f32_16x16x32_bf16(af[ks * 4 + m], bf0, acc[m][0], 0, 0, 0);
          acc[m][1] = __builtin_amdgcn_mfma_f32_16x16x32_bf16(af[ks * 4 + m], bf1, acc[m][1], 0, 0, 0);
        }
      }
    }
    // ---- k-half 1 ----
    {
      const short8* Bv = (const short8*)(bufR + 1024 * 8);
#pragma unroll
      for (int ks = 0; ks < 4; ++ks) {
        const short8 bf0 = Bv[cc0 * 16 + ((ks * 4 + kq_l) ^ (cc0 & 15))];
        const short8 bf1 = Bv[cc1 * 16 + ((ks * 4 + kq_l) ^ (cc1 & 15))];
#pragma unroll
        for (int m = 0; m < 4; ++m) {
          acc[m][0] = __builtin_amdgcn_mfma_f32_16x16x32_bf16(af[(4 + ks) * 4 + m], bf0, acc[m][0], 0, 0, 0);
          acc[m][1] = __builtin_amdgcn_mfma_f32_16x16x32_bf16(af[(4 + ks) * 4 + m], bf1, acc[m][1], 0, 0, 0);
        }
      }
    }

    // ---- epilogue: masked running max/min on g = sq_c - 2*acc ----
    {
      const float2 sl0 = sl_s[ct * 64 + cc0];
      const float2 sl1 = sl_s[ct * 64 + cc1];
#pragma unroll
      for (int n = 0; n < 2; ++n) {
        const float sc = (n == 0) ? sl0.x : sl1.x;
        const int lc = __float_as_int((n == 0) ? sl0.y : sl1.y);
#pragma unroll
        for (int idx = 0; idx < 16; ++idx) {
          const int m = idx >> 2, q = idx & 3;
          const float g = fmaf(-2.0f, acc[m][n][q], sc);
          const int lr = (labp[idx >> 1] >> ((idx & 1) * 16)) & 0xffff;
          const bool same = (lr == lc);
          pmax[idx] = same ? fmaxf(pmax[idx], g) : pmax[idx];
          nmin[idx] = same ? nmin[idx] : fminf(nmin[idx], g);
        }
      }
    }
    cur ^= 1;
  }

  // ---- reduce over 16 col-lanes, 2 atomics per row ----
#pragma unroll
  for (int i = 0; i < 16; ++i) {
    float p = pmax[i], nn2 = nmin[i];
#pragma unroll
    for (int off = 1; off < 16; off <<= 1) {
      p = fmaxf(p, __shfl_xor(p, off));
      nn2 = fminf(nn2, __shfl_xor(nn2, off));
    }
    if (c_l == 0) {
      const int rowg = rows0 + wr * 64 + (i >> 2) * 16 + kq_l * 4 + (i & 3);
      atomicMax(&pos2[rowg], enc_ord(p));
      atomicMin(&neg2[rowg], enc_ord(nn2));
    }
  }
}

// ---------------- K2a: hv + global extremes (parallel) ----------------
__global__ __launch_bounds__(512) void finalize_a_kernel(const float2* __restrict__ sqlab,
                                                         const unsigned int* __restrict__ pos2,
                                                         const unsigned int* __restrict__ neg2,
                                                         float* __restrict__ hv_g,
                                                         unsigned int* __restrict__ gmm) {
  const int i = blockIdx.x * 512 + threadIdx.x;
  const int lane = threadIdx.x & 63;
  const float s = sqlab[i].x;
  const float p2 = fmaxf(s + dec_ord(pos2[i]), 1e-12f);
  const float n2 = fmaxf(s + dec_ord(neg2[i]), 1e-12f);
  const float hv = sqrtf(p2) - sqrtf(n2);
  hv_g[i] = hv;
  float lmax = hv, lmin = hv;
#pragma unroll
  for (int off = 32; off >= 1; off >>= 1) {
    lmax = fmaxf(lmax, __shfl_xor(lmax, off));
    lmin = fminf(lmin, __shfl_xor(lmin, off));
  }
  if (lane == 0) {
    atomicMax(&gmm[0], enc_ord(lmax));
    atomicMin(&gmm[1], enc_ord(lmin));
  }
}

// ---------------- K2b: per-block histogram + per-bin hv sums (parallel) ----------------
__global__ __launch_bounds__(512) void finalize_b_kernel(const float* __restrict__ hv_g,
                                                         const unsigned int* __restrict__ gmm,
                                                         float* __restrict__ ghist,
                                                         float* __restrict__ ghsum) {
  __shared__ float hist_s[NBINS];
  __shared__ float hsum_s[NBINS];
  const int t = threadIdx.x;
  if (t < NBINS) { hist_s[t] = 0.0f; hsum_s[t] = 0.0f; }
  const float maxv = fmaxf(dec_ord(gmm[0]), 2.0f);
  const float minv = fminf(dec_ord(gmm[1]), -2.0f);
  const float bw = (maxv - minv) / (float)(NBINS - 1);
  __syncthreads();

  const int i = blockIdx.x * 512 + t;
  const float hv = hv_g[i];
  int lo = (int)floorf((hv - minv) / bw);
  lo = min(max(lo, 0), NBINS - 1);
  const int hi = min(lo + 1, NBINS - 1);
  const float alpha = 1.0f - (hv - minv - (float)lo * bw) / bw;
  atomicAdd(&hist_s[lo], alpha);
  atomicAdd(&hist_s[hi], 1.0f - alpha);
  atomicAdd(&hsum_s[lo], hv);  // weight uses bin_idx = lo (same floor+clip)
  __syncthreads();

  if (t < NBINS) {
    atomicAdd(&ghist[t], hist_s[t]);
    atomicAdd(&ghsum[t], hsum_s[t]);
  }
}

// ---------------- K2c: cdf + loss (one wave) ----------------
__global__ __launch_bounds__(64) void finalize_c_kernel(const float* __restrict__ ghist,
                                                        const float* __restrict__ ghsum,
                                                        float* __restrict__ out) {
  const int t = threadIdx.x;
  const float h = ghist[t];
  float total = h;
#pragma unroll
  for (int off = 32; off >= 1; off >>= 1) total += __shfl_xor(total, off);
  const float hn = h / (total + 1e-6f);
  float s2 = hn;
#pragma unroll
  for (int off = 32; off >= 1; off >>= 1) s2 += __shfl_xor(s2, off);
  const float pdf = hn / s2;
  float c = pdf;
#pragma unroll
  for (int off = 1; off < 64; off <<= 1) {
    const float u = __shfl_up(c, off);
    if (t >= off) c += u;
  }
  float acc = c * ghsum[t];
#pragma unroll
  for (int off = 32; off >= 1; off >>= 1) acc += __shfl_xor(acc, off);
  if (t == 0) out[0] = acc / (float)Nn;
}

// ---------------- launch ----------------
extern "C" void kernel_launch(void* const* d_in, const int* in_sizes, int n_in,
                              void* d_out, int out_size, void* d_ws, size_t ws_size,
                              hipStream_t stream) {
  const float* x = (const float*)d_in[0];
  const int* targets = (const int*)d_in[1];
  float* out = (float*)d_out;

  char* p = (char*)d_ws;
  unsigned short* xb = (unsigned short*)p;  p += (size_t)Nn * Dd * 2;  // 4MB
  float2* sqlab = (float2*)p;               p += (size_t)Nn * 8;
  unsigned int* pos2 = (unsigned int*)p;    p += (size_t)Nn * 4;
  unsigned int* neg2 = (unsigned int*)p;    p += (size_t)Nn * 4;
  float* hv_g = (float*)p;                  p += (size_t)Nn * 4;
  unsigned int* gmm = (unsigned int*)p;     p += 64;
  float* ghist = (float*)p;                 p += NBINS * 4;
  float* ghsum = (float*)p;

  prep_kernel<<<Nn / 4, 256, 0, stream>>>(x, targets, xb, sqlab, pos2, neg2, gmm, ghist, ghsum);
  pairwise_kernel<<<dim3(Nn / 128, NSPLIT), 256, 0, stream>>>(xb, sqlab, pos2, neg2);
  finalize_a_kernel<<<Nn / 512, 512, 0, stream>>>(sqlab, pos2, neg2, hv_g, gmm);
  finalize_b_kernel<<<Nn / 512, 512, 0, stream>>>(hv_g, gmm, ghist, ghsum);
  finalize_c_kernel<<<1, 64, 0, stream>>>(ghist, ghsum, out);
}